// Round 5
// baseline (558.241 us; speedup 1.0000x reference)
//
#include <hip/hip_runtime.h>
#include <hip/hip_bf16.h>

typedef __attribute__((ext_vector_type(8))) short short8_t;
typedef __attribute__((ext_vector_type(4))) float f32x4;
typedef float f32x4u __attribute__((ext_vector_type(4), aligned(4)));  // 4B-aligned vector load

#define NNODES 50000
#define FIN 1433
#define HID 128
#define NCLS 7
#define KT1 23          // ceil(1433/64)
#define BK 64
#define BM 64

static __device__ __forceinline__ unsigned short f2bf(float f) {
    union { float f; unsigned int u; } v; v.f = f;
    unsigned int u = v.u;
    u += 0x7FFFu + ((u >> 16) & 1u);   // round-to-nearest-even
    return (unsigned short)(u >> 16);
}
static __device__ __forceinline__ float bf2f(unsigned short b) {
    union { unsigned int u; float f; } v; v.u = ((unsigned int)b) << 16; return v.f;
}

// ---------------- degree / norm ----------------
__global__ void init_deg(int* deg, int n) {
    int i = blockIdx.x * blockDim.x + threadIdx.x;
    if (i < n) deg[i] = 1;              // self loop
}

__global__ void count_deg(const int* __restrict__ dst, int E, int* deg, int n) {
    int e = blockIdx.x * blockDim.x + threadIdx.x;
    if (e < E) {
        int d = dst[e];
        if ((unsigned)d < (unsigned)n) atomicAdd(&deg[d], 1);
    }
}

__global__ void calc_dinv(const int* __restrict__ deg, float* dinv, int n) {
    int i = blockIdx.x * blockDim.x + threadIdx.x;
    if (i < n) dinv[i] = rsqrtf((float)deg[i]);
}

// ---------------- CSR build ----------------
__global__ void scan_deg(const int* __restrict__ deg, int* ptr, int* cursor, int n) {
    __shared__ int sums[1024];
    int t = threadIdx.x;
    const int CH = (n + 1023) / 1024;
    int start = t * CH, end = min(start + CH, n);
    int s = 0;
    for (int i = start; i < end; ++i) s += deg[i] - 1;
    sums[t] = s;
    __syncthreads();
    for (int off = 1; off < 1024; off <<= 1) {
        int v = (t >= off) ? sums[t - off] : 0;
        __syncthreads();
        sums[t] += v;
        __syncthreads();
    }
    int base = (t == 0) ? 0 : sums[t - 1];
    for (int i = start; i < end; ++i) {
        ptr[i] = base; cursor[i] = base;
        base += deg[i] - 1;
    }
}

__global__ void fill_csr(const int* __restrict__ src, const int* __restrict__ dst,
                         int E, int* cursor, int* csr, int n) {
    int e = blockIdx.x * blockDim.x + threadIdx.x;
    if (e < E) {
        int d = dst[e], s = src[e];
        if ((unsigned)d < (unsigned)n && (unsigned)s < (unsigned)n) {
            int pos = atomicAdd(&cursor[d], 1);
            csr[pos] = s;
        }
    }
}

// ---------------- W1 pack: W1[FIN][HID] f32 -> W1s[KT1][1024 segs][8 bf16]
// seg = g*128 + c  (g = k-octet within BK tile, c = output col); LDS-tile order.
__global__ void prep_w1(const float* __restrict__ W1, unsigned short* __restrict__ W1s) {
    int tid = blockIdx.x * 256 + threadIdx.x;
    if (tid >= KT1 * 1024) return;
    int kt = tid >> 10, seg = tid & 1023;
    int c = seg & 127, g = seg >> 7;
    int kb = kt * BK + g * 8;
    unsigned int w[4];
    #pragma unroll
    for (int p = 0; p < 4; ++p) {
        int k0 = kb + p * 2, k1 = kb + p * 2 + 1;
        unsigned short lo = (k0 < FIN) ? f2bf(W1[(size_t)k0 * HID + c]) : (unsigned short)0;
        unsigned short hi = (k1 < FIN) ? f2bf(W1[(size_t)k1 * HID + c]) : (unsigned short)0;
        w[p] = (unsigned int)lo | ((unsigned int)hi << 16);
    }
    uint4* dstp = (uint4*)(W1s + (size_t)tid * 8);
    uint4 val; val.x = w[0]; val.y = w[1]; val.z = w[2]; val.w = w[3];
    *dstp = val;
}

// ---------------- GEMM1: h[M][128] (bf16) = x[M][1433] @ W1 ----------------
// BM=64, BK=64, 256 threads / 4 waves (2x2 over 64 rows x 128 cols).
// Double-buffered LDS, ONE barrier per K-iter, A reg-staged, B via
// global_load_lds from pre-packed W1s. 48KB LDS -> 3 blocks/CU, grid 782.
__global__ __launch_bounds__(256, 3) void gemm1(const float* __restrict__ x,
                                                const unsigned short* __restrict__ W1s,
                                                unsigned short* __restrict__ h, int M) {
    // A: [row 64][(g*8) ^ ((row&7)<<3) ..+7] ushorts (XOR-swizzled, 8KB/buf)
    // B: [g 8][c 128][8] ushorts (linear, gload_lds order, 16KB/buf)
    __shared__ unsigned short As[2][4096];
    __shared__ unsigned short Bs[2][8192];
    const int t = threadIdx.x;
    const int wave = t >> 6, lane = t & 63;
    const int wm = wave >> 1, wn = wave & 1;
    const int r = lane & 15, u = lane >> 4;
    const int rowBase = blockIdx.x * BM;
    f32x4 acc[2][4] = {};

    float4 areg[4];

    auto issueA = [&](int kt) {
        int k0 = kt * BK;
        #pragma unroll
        for (int i = 0; i < 4; ++i) {
            int quad = i * 256 + t;
            int row = quad >> 4, kq = quad & 15;
            int gr = rowBase + row;
            int gk = k0 + kq * 4;
            if (gr < M && gk + 3 < FIN) {
                f32x4u v = *(const f32x4u*)(x + (size_t)gr * FIN + gk);
                areg[i].x = v.x; areg[i].y = v.y; areg[i].z = v.z; areg[i].w = v.w;
            } else {
                areg[i].x = (gr < M && gk + 0 < FIN) ? x[(size_t)gr * FIN + gk + 0] : 0.f;
                areg[i].y = (gr < M && gk + 1 < FIN) ? x[(size_t)gr * FIN + gk + 1] : 0.f;
                areg[i].z = (gr < M && gk + 2 < FIN) ? x[(size_t)gr * FIN + gk + 2] : 0.f;
                areg[i].w = (gr < M && gk + 3 < FIN) ? x[(size_t)gr * FIN + gk + 3] : 0.f;
            }
        }
    };
    auto issueB = [&](int kt, int buf) {
        #pragma unroll
        for (int i = 0; i < 4; ++i) {
            const unsigned short* gp = W1s + ((size_t)kt * 1024 + (size_t)(i * 256 + t)) * 8;
            unsigned short* lp = &Bs[buf][(i * 256 + wave * 64) * 8];
            __builtin_amdgcn_global_load_lds(
                (const __attribute__((address_space(1))) unsigned int*)gp,
                (__attribute__((address_space(3))) unsigned int*)lp, 16, 0, 0);
        }
    };
    auto writeA = [&](int buf) {
        #pragma unroll
        for (int i = 0; i < 4; ++i) {
            int quad = i * 256 + t;
            int row = quad >> 4, kq = quad & 15;
            unsigned int lo = (unsigned int)f2bf(areg[i].x) | ((unsigned int)f2bf(areg[i].y) << 16);
            unsigned int hi = (unsigned int)f2bf(areg[i].z) | ((unsigned int)f2bf(areg[i].w) << 16);
            unsigned long long pk = ((unsigned long long)hi << 32) | (unsigned long long)lo;
            int us = row * 64 + ((kq * 4) ^ ((row & 7) << 3));
            *(unsigned long long*)(&As[buf][us]) = pk;
        }
    };
    auto compute = [&](int buf) {
        short8_t af[2][2], bfr[2][4];
        #pragma unroll
        for (int ks = 0; ks < 2; ++ks) {
            int g = ks * 4 + u;
            #pragma unroll
            for (int mi = 0; mi < 2; ++mi) {
                int row = wm * 32 + mi * 16 + r;
                int us = row * 64 + ((g * 8) ^ ((row & 7) << 3));
                af[ks][mi] = *(const short8_t*)(&As[buf][us]);
            }
            #pragma unroll
            for (int ni = 0; ni < 4; ++ni) {
                int c = wn * 64 + ni * 16 + r;
                bfr[ks][ni] = *(const short8_t*)(&Bs[buf][g * 1024 + c * 8]);
            }
        }
        #pragma unroll
        for (int ks = 0; ks < 2; ++ks)
            #pragma unroll
            for (int mi = 0; mi < 2; ++mi)
                #pragma unroll
                for (int ni = 0; ni < 4; ++ni)
                    acc[mi][ni] = __builtin_amdgcn_mfma_f32_16x16x32_bf16(af[ks][mi], bfr[ks][ni], acc[mi][ni], 0, 0, 0);
    };

    // prologue: stage tile 0
    issueA(0);
    issueB(0, 0);
    writeA(0);                 // auto vmcnt wait on A loads
    __syncthreads();           // drains B gload_lds + makes A writes visible

    int cur = 0;
    for (int kt = 0; kt < KT1; ++kt) {
        int nxt = cur ^ 1;
        if (kt + 1 < KT1) { issueA(kt + 1); issueB(kt + 1, nxt); }
        compute(cur);
        if (kt + 1 < KT1) writeA(nxt);   // A[nxt] readers retired before previous barrier
        __syncthreads();                 // one barrier/iter
        cur = nxt;
    }

    // epilogue: C layout col=lane&15, row=(lane>>4)*4+reg
    #pragma unroll
    for (int mi = 0; mi < 2; ++mi) {
        #pragma unroll
        for (int reg = 0; reg < 4; ++reg) {
            int grow = rowBase + wm * 32 + mi * 16 + u * 4 + reg;
            if (grow < M) {
                #pragma unroll
                for (int ni = 0; ni < 4; ++ni) {
                    int gcol = wn * 64 + ni * 16 + r;
                    h[(size_t)grow * HID + gcol] = f2bf(acc[mi][ni][reg]);
                }
            }
        }
    }
}

// ---------------- Aggregation 1 + bias + relu + @W2 fused ----------------
// one wave per node; lane = (row-group g = lane>>4) x (feature-octet fr = lane&15)
// 4 neighbor rows in flight per wave-instruction, 16B loads.
__global__ __launch_bounds__(256) void agg1(const unsigned short* __restrict__ h,
                                            const int* __restrict__ ptr,
                                            const int* __restrict__ deg,
                                            const int* __restrict__ csr,
                                            const float* __restrict__ dinv,
                                            const float* __restrict__ b1,
                                            const float* __restrict__ W2,
                                            float* __restrict__ h2s, int n) {
    __shared__ float W2s[HID * NCLS];
    for (int i = threadIdx.x; i < HID * NCLS; i += 256) W2s[i] = W2[i];
    __syncthreads();
    int wave = threadIdx.x >> 6, lane = threadIdx.x & 63;
    int v = blockIdx.x * 4 + wave;
    if (v >= n) return;
    const int fr = lane & 15, g = lane >> 4;
    float dv = dinv[v];
    int p0 = ptr[v];
    int total = deg[v];                 // in-edges + self
    float acc[8] = {};
    #pragma unroll 2
    for (int ri = g; ri < total; ri += 4) {
        int s = (ri == 0) ? v : csr[p0 + ri - 1];
        float nrm = (ri == 0) ? dv * dv : dv * dinv[s];
        uint4 q = *(const uint4*)(h + (size_t)s * HID + fr * 8);
        unsigned int w[4] = {q.x, q.y, q.z, q.w};
        #pragma unroll
        for (int p = 0; p < 4; ++p) {
            acc[p * 2 + 0] += nrm * bf2f((unsigned short)(w[p] & 0xffffu));
            acc[p * 2 + 1] += nrm * bf2f((unsigned short)(w[p] >> 16));
        }
    }
    // combine the 4 row-groups
    #pragma unroll
    for (int e = 0; e < 8; ++e) {
        acc[e] += __shfl_xor(acc[e], 16, 64);
        acc[e] += __shfl_xor(acc[e], 32, 64);
    }
    // bias + relu + W2 projection (each lane: features fr*8..fr*8+7)
    float p[NCLS];
    #pragma unroll
    for (int c = 0; c < NCLS; ++c) p[c] = 0.f;
    #pragma unroll
    for (int e = 0; e < 8; ++e) {
        int f = fr * 8 + e;
        float val = fmaxf(acc[e] + b1[f], 0.f);
        #pragma unroll
        for (int c = 0; c < NCLS; ++c) p[c] += val * W2s[f * NCLS + c];
    }
    #pragma unroll
    for (int off = 8; off >= 1; off >>= 1)
        #pragma unroll
        for (int c = 0; c < NCLS; ++c)
            p[c] += __shfl_xor(p[c], off, 64);
    if (lane == 0) {
        #pragma unroll
        for (int c = 0; c < NCLS; ++c) h2s[(size_t)v * 8 + c] = p[c];
        h2s[(size_t)v * 8 + 7] = 0.f;
    }
}

// ---------------- Aggregation 2 + bias ----------------
// 32 lanes per node: 4 edge-groups x 8 feature-lanes; 2 nodes per wave.
__global__ __launch_bounds__(256) void agg2(const float* __restrict__ h2s,
                                            const int* __restrict__ ptr,
                                            const int* __restrict__ deg,
                                            const int* __restrict__ csr,
                                            const float* __restrict__ dinv,
                                            const float* __restrict__ b2,
                                            float* __restrict__ out, int n) {
    int wave = threadIdx.x >> 6, lane = threadIdx.x & 63;
    int half = lane >> 5;
    int c = lane & 7, g = (lane >> 3) & 3;
    int v = blockIdx.x * 8 + wave * 2 + half;
    if (v >= n) return;
    float dv = dinv[v];
    int p0 = ptr[v], total = deg[v];
    float acc = 0.f;
    #pragma unroll 2
    for (int ri = g; ri < total; ri += 4) {
        int s = (ri == 0) ? v : csr[p0 + ri - 1];
        float nrm = (ri == 0) ? dv * dv : dv * dinv[s];
        acc += nrm * h2s[(size_t)s * 8 + c];
    }
    acc += __shfl_xor(acc, 8, 64);
    acc += __shfl_xor(acc, 16, 64);
    if (g == 0 && c < NCLS) out[(size_t)v * NCLS + c] = acc + b2[c];
}

extern "C" void kernel_launch(void* const* d_in, const int* in_sizes, int n_in,
                              void* d_out, int out_size, void* d_ws, size_t ws_size,
                              hipStream_t stream) {
    const float* x  = (const float*)d_in[0];
    const int*   ei = (const int*)d_in[1];    // int64 in reference but JAX x64-off => int32
    const float* W1 = (const float*)d_in[2];
    const float* b1 = (const float*)d_in[3];
    const float* W2 = (const float*)d_in[4];
    const float* b2 = (const float*)d_in[5];
    float* out = (float*)d_out;

    const int N = NNODES;
    const int E = in_sizes[1] / 2;
    const int* src = ei;
    const int* dst = ei + E;

    char* ws = (char*)d_ws;
    size_t off = 0;
    auto alloc = [&](size_t bytes) {
        void* p = ws + off;
        off += (bytes + 255) & ~(size_t)255;
        return p;
    };
    int*   deg    = (int*)alloc((size_t)N * 4);
    float* dinv   = (float*)alloc((size_t)N * 4);
    int*   ptr    = (int*)alloc((size_t)N * 4);
    int*   cursor = (int*)alloc((size_t)N * 4);
    int*   csr    = (int*)alloc((size_t)E * 4);
    unsigned short* W1s = (unsigned short*)alloc((size_t)KT1 * 1024 * 8 * 2);
    unsigned short* h   = (unsigned short*)alloc((size_t)N * HID * 2);
    float* h2s    = (float*)alloc((size_t)N * 8 * 4);

    init_deg<<<(N + 255) / 256, 256, 0, stream>>>(deg, N);
    count_deg<<<(E + 255) / 256, 256, 0, stream>>>(dst, E, deg, N);
    calc_dinv<<<(N + 255) / 256, 256, 0, stream>>>(deg, dinv, N);
    scan_deg<<<1, 1024, 0, stream>>>(deg, ptr, cursor, N);
    fill_csr<<<(E + 255) / 256, 256, 0, stream>>>(src, dst, E, cursor, csr, N);
    prep_w1<<<(KT1 * 1024 + 255) / 256, 256, 0, stream>>>(W1, W1s);
    gemm1<<<(N + BM - 1) / BM, 256, 0, stream>>>(x, W1s, h, N);
    agg1<<<(N + 3) / 4, 256, 0, stream>>>(h, ptr, deg, csr, dinv, b1, W2, h2s, N);
    agg2<<<(N + 7) / 8, 256, 0, stream>>>(h2s, ptr, deg, csr, dinv, b2, out, N);
}

// Round 6
// 498.602 us; speedup vs baseline: 1.1196x; 1.1196x over previous
//
#include <hip/hip_runtime.h>
#include <hip/hip_bf16.h>

typedef __attribute__((ext_vector_type(8))) short short8_t;
typedef __attribute__((ext_vector_type(4))) float f32x4;
typedef float f32x4u __attribute__((ext_vector_type(4), aligned(4)));  // 4B-aligned vector load

#define NNODES 50000
#define FIN 1433
#define HID 128
#define NCLS 7
#define KT1 23          // ceil(1433/64)
#define BK 64
#define BM 128

static __device__ __forceinline__ unsigned short f2bf(float f) {
    union { float f; unsigned int u; } v; v.f = f;
    unsigned int u = v.u;
    u += 0x7FFFu + ((u >> 16) & 1u);   // round-to-nearest-even
    return (unsigned short)(u >> 16);
}
static __device__ __forceinline__ float bf2f(unsigned short b) {
    union { unsigned int u; float f; } v; v.u = ((unsigned int)b) << 16; return v.f;
}

// ---------------- degree / norm ----------------
__global__ void init_deg(int* deg, int n) {
    int i = blockIdx.x * blockDim.x + threadIdx.x;
    if (i < n) deg[i] = 1;              // self loop
}

__global__ void count_deg(const int* __restrict__ dst, int E, int* deg, int n) {
    int e = blockIdx.x * blockDim.x + threadIdx.x;
    if (e < E) {
        int d = dst[e];
        if ((unsigned)d < (unsigned)n) atomicAdd(&deg[d], 1);
    }
}

__global__ void calc_dinv(const int* __restrict__ deg, float* dinv, int n) {
    int i = blockIdx.x * blockDim.x + threadIdx.x;
    if (i < n) dinv[i] = rsqrtf((float)deg[i]);
}

// ---------------- CSR build (self-loops INCLUDED in csr) ----------------
__global__ void scan_deg(const int* __restrict__ deg, int* ptr, int* cursor, int n) {
    __shared__ int sums[1024];
    int t = threadIdx.x;
    const int CH = (n + 1023) / 1024;
    int start = t * CH, end = min(start + CH, n);
    int s = 0;
    for (int i = start; i < end; ++i) s += deg[i];
    sums[t] = s;
    __syncthreads();
    for (int off = 1; off < 1024; off <<= 1) {
        int v = (t >= off) ? sums[t - off] : 0;
        __syncthreads();
        sums[t] += v;
        __syncthreads();
    }
    int base = (t == 0) ? 0 : sums[t - 1];
    for (int i = start; i < end; ++i) {
        ptr[i] = base; cursor[i] = base;
        base += deg[i];
    }
}

__global__ void fill_csr(const int* __restrict__ src, const int* __restrict__ dst,
                         int E, int* cursor, int* csr, int n) {
    int e = blockIdx.x * blockDim.x + threadIdx.x;
    if (e < E) {
        int d = dst[e], s = src[e];
        if ((unsigned)d < (unsigned)n && (unsigned)s < (unsigned)n) {
            int pos = atomicAdd(&cursor[d], 1);
            csr[pos] = s;
        }
    }
}

__global__ void fill_self(int* cursor, int* csr, int n) {
    int v = blockIdx.x * blockDim.x + threadIdx.x;
    if (v < n) {
        int pos = atomicAdd(&cursor[v], 1);
        csr[pos] = v;
    }
}

// ---------------- W1 pack: W1[FIN][HID] f32 -> W1s[KT1][1024 segs][8 bf16]
// seg = g*128 + c  (g = k-octet within BK tile, c = output col); LDS-tile order.
__global__ void prep_w1(const float* __restrict__ W1, unsigned short* __restrict__ W1s) {
    int tid = blockIdx.x * 256 + threadIdx.x;
    if (tid >= KT1 * 1024) return;
    int kt = tid >> 10, seg = tid & 1023;
    int c = seg & 127, g = seg >> 7;
    int kb = kt * BK + g * 8;
    unsigned int w[4];
    #pragma unroll
    for (int p = 0; p < 4; ++p) {
        int k0 = kb + p * 2, k1 = kb + p * 2 + 1;
        unsigned short lo = (k0 < FIN) ? f2bf(W1[(size_t)k0 * HID + c]) : (unsigned short)0;
        unsigned short hi = (k1 < FIN) ? f2bf(W1[(size_t)k1 * HID + c]) : (unsigned short)0;
        w[p] = (unsigned int)lo | ((unsigned int)hi << 16);
    }
    uint4* dstp = (uint4*)(W1s + (size_t)tid * 8);
    uint4 val; val.x = w[0]; val.y = w[1]; val.z = w[2]; val.w = w[3];
    *dstp = val;
}

// ---------------- GEMM1: h'[M][128] (bf16) = dinv[r] * (x[M][1433] @ W1) ----
// BM=128, BK=64, 512 threads / 8 waves (4 row-groups x 2 col-groups).
// Double-buffered LDS, ONE barrier per K-iter, A reg-staged (packed cvt),
// B via global_load_lds from pre-packed W1s. Output pre-scaled by dinv[row].
__global__ __launch_bounds__(512, 4) void gemm1(const float* __restrict__ x,
                                                const unsigned short* __restrict__ W1s,
                                                const float* __restrict__ dinv,
                                                unsigned short* __restrict__ h, int M) {
    // A: [row 128][(g*8) ^ ((row&7)<<3) ..+7] ushorts (XOR-swizzled, 16KB/buf)
    // B: [g 8][c 128][8] ushorts (linear, gload_lds order, 16KB/buf)
    __shared__ unsigned short As[2][8192];
    __shared__ unsigned short Bs[2][8192];
    const int t = threadIdx.x;
    const int wave = t >> 6, lane = t & 63;
    const int wm = wave >> 1, wn = wave & 1;
    const int r = lane & 15, u = lane >> 4;
    const int rowBase = blockIdx.x * BM;
    f32x4 acc[2][4] = {};

    float4 areg[4];

    auto issueA = [&](int kt) {
        int k0 = kt * BK;
        #pragma unroll
        for (int i = 0; i < 4; ++i) {
            int quad = i * 512 + t;
            int row = quad >> 4, kq = quad & 15;
            int gr = rowBase + row;
            int gk = k0 + kq * 4;
            if (gr < M && gk + 3 < FIN) {
                f32x4u v = *(const f32x4u*)(x + (size_t)gr * FIN + gk);
                areg[i].x = v.x; areg[i].y = v.y; areg[i].z = v.z; areg[i].w = v.w;
            } else {
                areg[i].x = (gr < M && gk + 0 < FIN) ? x[(size_t)gr * FIN + gk + 0] : 0.f;
                areg[i].y = (gr < M && gk + 1 < FIN) ? x[(size_t)gr * FIN + gk + 1] : 0.f;
                areg[i].z = (gr < M && gk + 2 < FIN) ? x[(size_t)gr * FIN + gk + 2] : 0.f;
                areg[i].w = (gr < M && gk + 3 < FIN) ? x[(size_t)gr * FIN + gk + 3] : 0.f;
            }
        }
    };
    auto issueB = [&](int kt, int buf) {
        #pragma unroll
        for (int i = 0; i < 2; ++i) {
            const unsigned short* gp = W1s + ((size_t)kt * 1024 + (size_t)(i * 512 + t)) * 8;
            unsigned short* lp = &Bs[buf][(i * 512 + wave * 64) * 8];
            __builtin_amdgcn_global_load_lds(
                (const __attribute__((address_space(1))) unsigned int*)gp,
                (__attribute__((address_space(3))) unsigned int*)lp, 16, 0, 0);
        }
    };
    auto writeA = [&](int buf) {
        #pragma unroll
        for (int i = 0; i < 4; ++i) {
            int quad = i * 512 + t;
            int row = quad >> 4, kq = quad & 15;
            __hip_bfloat162 lo2 = __float22bfloat162_rn(make_float2(areg[i].x, areg[i].y));
            __hip_bfloat162 hi2 = __float22bfloat162_rn(make_float2(areg[i].z, areg[i].w));
            unsigned int ulo, uhi;
            __builtin_memcpy(&ulo, &lo2, 4);
            __builtin_memcpy(&uhi, &hi2, 4);
            unsigned long long pk = ((unsigned long long)uhi << 32) | (unsigned long long)ulo;
            int us = row * 64 + ((kq * 4) ^ ((row & 7) << 3));
            *(unsigned long long*)(&As[buf][us]) = pk;
        }
    };
    auto compute = [&](int buf) {
        short8_t af[2][2], bfr[2][4];
        #pragma unroll
        for (int ks = 0; ks < 2; ++ks) {
            int g = ks * 4 + u;
            #pragma unroll
            for (int mi = 0; mi < 2; ++mi) {
                int row = wm * 32 + mi * 16 + r;
                int us = row * 64 + ((g * 8) ^ ((row & 7) << 3));
                af[ks][mi] = *(const short8_t*)(&As[buf][us]);
            }
            #pragma unroll
            for (int ni = 0; ni < 4; ++ni) {
                int c = wn * 64 + ni * 16 + r;
                bfr[ks][ni] = *(const short8_t*)(&Bs[buf][g * 1024 + c * 8]);
            }
        }
        #pragma unroll
        for (int ks = 0; ks < 2; ++ks)
            #pragma unroll
            for (int mi = 0; mi < 2; ++mi)
                #pragma unroll
                for (int ni = 0; ni < 4; ++ni)
                    acc[mi][ni] = __builtin_amdgcn_mfma_f32_16x16x32_bf16(af[ks][mi], bfr[ks][ni], acc[mi][ni], 0, 0, 0);
    };

    // prologue: stage tile 0
    issueA(0);
    issueB(0, 0);
    writeA(0);                 // auto vmcnt wait on A loads
    __syncthreads();           // drains B gload_lds + makes A writes visible

    int cur = 0;
    for (int kt = 0; kt < KT1; ++kt) {
        int nxt = cur ^ 1;
        if (kt + 1 < KT1) { issueA(kt + 1); issueB(kt + 1, nxt); }
        compute(cur);
        if (kt + 1 < KT1) writeA(nxt);   // A[nxt] readers retired before previous barrier
        __syncthreads();                 // one barrier/iter
        cur = nxt;
    }

    // epilogue: C layout col=lane&15, row=(lane>>4)*4+reg; pre-scale by dinv[row]
    #pragma unroll
    for (int mi = 0; mi < 2; ++mi) {
        #pragma unroll
        for (int reg = 0; reg < 4; ++reg) {
            int grow = rowBase + wm * 32 + mi * 16 + u * 4 + reg;
            if (grow < M) {
                float dv = dinv[grow];
                #pragma unroll
                for (int ni = 0; ni < 4; ++ni) {
                    int gcol = wn * 64 + ni * 16 + r;
                    h[(size_t)grow * HID + gcol] = f2bf(dv * acc[mi][ni][reg]);
                }
            }
        }
    }
}

// ---------------- Aggregation 1 + bias + relu + @W2 fused ----------------
// h is pre-scaled by dinv[src]; csr includes self-loop -> branchless sum.
// one wave per node; lane = (row-group g = lane>>4) x (feature-octet fr = lane&15)
__global__ __launch_bounds__(256) void agg1(const unsigned short* __restrict__ h,
                                            const int* __restrict__ ptr,
                                            const int* __restrict__ deg,
                                            const int* __restrict__ csr,
                                            const float* __restrict__ dinv,
                                            const float* __restrict__ b1,
                                            const float* __restrict__ W2,
                                            float* __restrict__ h2s, int n) {
    __shared__ float W2s[HID * NCLS];
    for (int i = threadIdx.x; i < HID * NCLS; i += 256) W2s[i] = W2[i];
    __syncthreads();
    int wave = threadIdx.x >> 6, lane = threadIdx.x & 63;
    int v = blockIdx.x * 4 + wave;
    if (v >= n) return;
    const int fr = lane & 15, g = lane >> 4;
    int p0 = ptr[v];
    int total = deg[v];                 // in-edges + self (all in csr)
    float acc[8] = {};
    #pragma unroll 4
    for (int j = g; j < total; j += 4) {
        int s = csr[p0 + j];
        uint4 q = *(const uint4*)(h + (size_t)s * HID + fr * 8);
        unsigned int w[4] = {q.x, q.y, q.z, q.w};
        #pragma unroll
        for (int p = 0; p < 4; ++p) {
            acc[p * 2 + 0] += bf2f((unsigned short)(w[p] & 0xffffu));
            acc[p * 2 + 1] += bf2f((unsigned short)(w[p] >> 16));
        }
    }
    // combine the 4 row-groups
    #pragma unroll
    for (int e = 0; e < 8; ++e) {
        acc[e] += __shfl_xor(acc[e], 16, 64);
        acc[e] += __shfl_xor(acc[e], 32, 64);
    }
    float dv = dinv[v];
    // bias + relu + W2 projection (each lane: features fr*8..fr*8+7)
    float p[NCLS];
    #pragma unroll
    for (int c = 0; c < NCLS; ++c) p[c] = 0.f;
    #pragma unroll
    for (int e = 0; e < 8; ++e) {
        int f = fr * 8 + e;
        float val = fmaxf(dv * acc[e] + b1[f], 0.f);
        #pragma unroll
        for (int c = 0; c < NCLS; ++c) p[c] += val * W2s[f * NCLS + c];
    }
    #pragma unroll
    for (int off = 8; off >= 1; off >>= 1)
        #pragma unroll
        for (int c = 0; c < NCLS; ++c)
            p[c] += __shfl_xor(p[c], off, 64);
    if (lane == 0) {
        #pragma unroll
        for (int c = 0; c < NCLS; ++c) h2s[(size_t)v * 8 + c] = dv * p[c];  // pre-scaled
        h2s[(size_t)v * 8 + 7] = 0.f;
    }
}

// ---------------- Aggregation 2 + bias ----------------
// h2s pre-scaled by dinv[src]; csr includes self. 32 lanes/node: 4 edge-groups
// x 8 feature-lanes; 2 nodes per wave.
__global__ __launch_bounds__(256) void agg2(const float* __restrict__ h2s,
                                            const int* __restrict__ ptr,
                                            const int* __restrict__ deg,
                                            const int* __restrict__ csr,
                                            const float* __restrict__ dinv,
                                            const float* __restrict__ b2,
                                            float* __restrict__ out, int n) {
    int wave = threadIdx.x >> 6, lane = threadIdx.x & 63;
    int half = lane >> 5;
    int c = lane & 7, g = (lane >> 3) & 3;
    int v = blockIdx.x * 8 + wave * 2 + half;
    if (v >= n) return;
    int p0 = ptr[v], total = deg[v];
    float acc = 0.f;
    #pragma unroll 4
    for (int j = g; j < total; j += 4) {
        int s = csr[p0 + j];
        acc += h2s[(size_t)s * 8 + c];
    }
    acc += __shfl_xor(acc, 8, 64);
    acc += __shfl_xor(acc, 16, 64);
    if (g == 0 && c < NCLS) out[(size_t)v * NCLS + c] = dinv[v] * acc + b2[c];
}

extern "C" void kernel_launch(void* const* d_in, const int* in_sizes, int n_in,
                              void* d_out, int out_size, void* d_ws, size_t ws_size,
                              hipStream_t stream) {
    const float* x  = (const float*)d_in[0];
    const int*   ei = (const int*)d_in[1];    // int64 in reference but JAX x64-off => int32
    const float* W1 = (const float*)d_in[2];
    const float* b1 = (const float*)d_in[3];
    const float* W2 = (const float*)d_in[4];
    const float* b2 = (const float*)d_in[5];
    float* out = (float*)d_out;

    const int N = NNODES;
    const int E = in_sizes[1] / 2;
    const int* src = ei;
    const int* dst = ei + E;

    char* ws = (char*)d_ws;
    size_t off = 0;
    auto alloc = [&](size_t bytes) {
        void* p = ws + off;
        off += (bytes + 255) & ~(size_t)255;
        return p;
    };
    int*   deg    = (int*)alloc((size_t)N * 4);
    float* dinv   = (float*)alloc((size_t)N * 4);
    int*   ptr    = (int*)alloc((size_t)N * 4);
    int*   cursor = (int*)alloc((size_t)N * 4);
    int*   csr    = (int*)alloc((size_t)(E + N) * 4);
    unsigned short* W1s = (unsigned short*)alloc((size_t)KT1 * 1024 * 8 * 2);
    unsigned short* h   = (unsigned short*)alloc((size_t)N * HID * 2);
    float* h2s    = (float*)alloc((size_t)N * 8 * 4);

    init_deg<<<(N + 255) / 256, 256, 0, stream>>>(deg, N);
    count_deg<<<(E + 255) / 256, 256, 0, stream>>>(dst, E, deg, N);
    calc_dinv<<<(N + 255) / 256, 256, 0, stream>>>(deg, dinv, N);
    scan_deg<<<1, 1024, 0, stream>>>(deg, ptr, cursor, N);
    fill_csr<<<(E + 255) / 256, 256, 0, stream>>>(src, dst, E, cursor, csr, N);
    fill_self<<<(N + 255) / 256, 256, 0, stream>>>(cursor, csr, N);
    prep_w1<<<(KT1 * 1024 + 255) / 256, 256, 0, stream>>>(W1, W1s);
    gemm1<<<(N + BM - 1) / BM, 512, 0, stream>>>(x, W1s, dinv, h, N);
    agg1<<<(N + 3) / 4, 256, 0, stream>>>(h, ptr, deg, csr, dinv, b1, W2, h2s, N);
    agg2<<<(N + 7) / 8, 256, 0, stream>>>(h2s, ptr, deg, csr, dinv, b2, out, N);
}

// Round 7
// 404.719 us; speedup vs baseline: 1.3793x; 1.2320x over previous
//
#include <hip/hip_runtime.h>
#include <hip/hip_bf16.h>

typedef __attribute__((ext_vector_type(8))) short short8_t;
typedef __attribute__((ext_vector_type(4))) float f32x4;
typedef float f32x4u __attribute__((ext_vector_type(4), aligned(4)));  // 4B-aligned vector load

#define NNODES 50000
#define FIN 1433
#define HID 128
#define NCLS 7
#define KT1 23          // ceil(1433/64)
#define BK 64
#define BM 128

static __device__ __forceinline__ unsigned short f2bf(float f) {
    union { float f; unsigned int u; } v; v.f = f;
    unsigned int u = v.u;
    u += 0x7FFFu + ((u >> 16) & 1u);   // round-to-nearest-even
    return (unsigned short)(u >> 16);
}
static __device__ __forceinline__ float bf2f(unsigned short b) {
    union { unsigned int u; float f; } v; v.u = ((unsigned int)b) << 16; return v.f;
}

// ---------------- degree / norm ----------------
__global__ void init_deg(int* deg, int n) {
    int i = blockIdx.x * blockDim.x + threadIdx.x;
    if (i < n) deg[i] = 1;              // self loop
}

// 4 edges per thread, int4 coalesced
__global__ void count_deg4(const int* __restrict__ dst, int E, int* deg) {
    int q = blockIdx.x * 256 + threadIdx.x;
    int i = q * 4;
    if (i + 3 < E) {
        int4 d = *(const int4*)(dst + i);
        atomicAdd(&deg[d.x], 1);
        atomicAdd(&deg[d.y], 1);
        atomicAdd(&deg[d.z], 1);
        atomicAdd(&deg[d.w], 1);
    } else if (i < E) {
        for (int e = i; e < E; ++e) atomicAdd(&deg[dst[e]], 1);
    }
}

__global__ void calc_dinv(const int* __restrict__ deg, float* dinv, int n) {
    int i = blockIdx.x * blockDim.x + threadIdx.x;
    if (i < n) dinv[i] = rsqrtf((float)deg[i]);
}

// ---------------- CSR build (self-loops INCLUDED in csr) ----------------
// 3-kernel parallel exclusive scan of deg -> ptr/cursor
__global__ void scan_part(const int* __restrict__ deg, int* __restrict__ blksum, int n) {
    __shared__ int ws[4];
    int i = blockIdx.x * 256 + threadIdx.x;
    int wave = threadIdx.x >> 6, lane = threadIdx.x & 63;
    int s = (i < n) ? deg[i] : 0;
    #pragma unroll
    for (int off = 1; off < 64; off <<= 1) s += __shfl_xor(s, off, 64);
    if (lane == 0) ws[wave] = s;
    __syncthreads();
    if (threadIdx.x == 0) blksum[blockIdx.x] = ws[0] + ws[1] + ws[2] + ws[3];
}

__global__ void scan_block(int* blksum, int nb) {   // one block, nb <= 256
    __shared__ int tmp[256];
    int t = threadIdx.x;
    int v = (t < nb) ? blksum[t] : 0;
    tmp[t] = v;
    __syncthreads();
    #pragma unroll
    for (int off = 1; off < 256; off <<= 1) {
        int u = (t >= off) ? tmp[t - off] : 0;
        __syncthreads();
        tmp[t] += u;
        __syncthreads();
    }
    if (t < nb) blksum[t] = tmp[t] - v;             // exclusive
}

__global__ void scan_apply(const int* __restrict__ deg, const int* __restrict__ blksum,
                           int* __restrict__ ptr, int* __restrict__ cursor, int n) {
    __shared__ int tmp[256];
    int t = threadIdx.x;
    int i = blockIdx.x * 256 + t;
    int v = (i < n) ? deg[i] : 0;
    tmp[t] = v;
    __syncthreads();
    #pragma unroll
    for (int off = 1; off < 256; off <<= 1) {
        int u = (t >= off) ? tmp[t - off] : 0;
        __syncthreads();
        tmp[t] += u;
        __syncthreads();
    }
    if (i < n) {
        int excl = blksum[blockIdx.x] + tmp[t] - v;
        ptr[i] = excl;
        cursor[i] = excl;
    }
}

// 4 edges per thread, int4 coalesced reads of src+dst
__global__ void fill_csr4(const int* __restrict__ src, const int* __restrict__ dst,
                          int E, int* cursor, int* csr) {
    int q = blockIdx.x * 256 + threadIdx.x;
    int i = q * 4;
    if (i + 3 < E) {
        int4 d = *(const int4*)(dst + i);
        int4 s = *(const int4*)(src + i);
        csr[atomicAdd(&cursor[d.x], 1)] = s.x;
        csr[atomicAdd(&cursor[d.y], 1)] = s.y;
        csr[atomicAdd(&cursor[d.z], 1)] = s.z;
        csr[atomicAdd(&cursor[d.w], 1)] = s.w;
    } else if (i < E) {
        for (int e = i; e < E; ++e)
            csr[atomicAdd(&cursor[dst[e]], 1)] = src[e];
    }
}

__global__ void fill_self(int* cursor, int* csr, int n) {
    int v = blockIdx.x * blockDim.x + threadIdx.x;
    if (v < n) {
        int pos = atomicAdd(&cursor[v], 1);
        csr[pos] = v;
    }
}

// ---------------- W1 pack: W1[FIN][HID] f32 -> W1s[KT1][1024 segs][8 bf16]
// seg = g*128 + c  (g = k-octet within BK tile, c = output col); LDS-tile order.
__global__ void prep_w1(const float* __restrict__ W1, unsigned short* __restrict__ W1s) {
    int tid = blockIdx.x * 256 + threadIdx.x;
    if (tid >= KT1 * 1024) return;
    int kt = tid >> 10, seg = tid & 1023;
    int c = seg & 127, g = seg >> 7;
    int kb = kt * BK + g * 8;
    unsigned int w[4];
    #pragma unroll
    for (int p = 0; p < 4; ++p) {
        int k0 = kb + p * 2, k1 = kb + p * 2 + 1;
        unsigned short lo = (k0 < FIN) ? f2bf(W1[(size_t)k0 * HID + c]) : (unsigned short)0;
        unsigned short hi = (k1 < FIN) ? f2bf(W1[(size_t)k1 * HID + c]) : (unsigned short)0;
        w[p] = (unsigned int)lo | ((unsigned int)hi << 16);
    }
    uint4* dstp = (uint4*)(W1s + (size_t)tid * 8);
    uint4 val; val.x = w[0]; val.y = w[1]; val.z = w[2]; val.w = w[3];
    *dstp = val;
}

// ---------------- GEMM1: h'[M][128] (bf16) = dinv[r] * (x[M][1433] @ W1) ----
// BM=128, BK=64, 512 threads / 8 waves (4 row-groups x 2 col-groups).
// Double-buffered LDS, ONE barrier per K-iter, A reg-staged (packed cvt),
// B via global_load_lds from pre-packed W1s. Output pre-scaled by dinv[row].
__global__ __launch_bounds__(512, 4) void gemm1(const float* __restrict__ x,
                                                const unsigned short* __restrict__ W1s,
                                                const float* __restrict__ dinv,
                                                unsigned short* __restrict__ h, int M) {
    // A: [row 128][(g*8) ^ ((row&7)<<3) ..+7] ushorts (XOR-swizzled, 16KB/buf)
    // B: [g 8][c 128][8] ushorts (linear, gload_lds order, 16KB/buf)
    __shared__ unsigned short As[2][8192];
    __shared__ unsigned short Bs[2][8192];
    const int t = threadIdx.x;
    const int wave = t >> 6, lane = t & 63;
    const int wm = wave >> 1, wn = wave & 1;
    const int r = lane & 15, u = lane >> 4;
    const int rowBase = blockIdx.x * BM;
    f32x4 acc[2][4] = {};

    float4 areg[4];

    auto issueA = [&](int kt) {
        int k0 = kt * BK;
        #pragma unroll
        for (int i = 0; i < 4; ++i) {
            int quad = i * 512 + t;
            int row = quad >> 4, kq = quad & 15;
            int gr = rowBase + row;
            int gk = k0 + kq * 4;
            if (gr < M && gk + 3 < FIN) {
                f32x4u v = *(const f32x4u*)(x + (size_t)gr * FIN + gk);
                areg[i].x = v.x; areg[i].y = v.y; areg[i].z = v.z; areg[i].w = v.w;
            } else {
                areg[i].x = (gr < M && gk + 0 < FIN) ? x[(size_t)gr * FIN + gk + 0] : 0.f;
                areg[i].y = (gr < M && gk + 1 < FIN) ? x[(size_t)gr * FIN + gk + 1] : 0.f;
                areg[i].z = (gr < M && gk + 2 < FIN) ? x[(size_t)gr * FIN + gk + 2] : 0.f;
                areg[i].w = (gr < M && gk + 3 < FIN) ? x[(size_t)gr * FIN + gk + 3] : 0.f;
            }
        }
    };
    auto issueB = [&](int kt, int buf) {
        #pragma unroll
        for (int i = 0; i < 2; ++i) {
            const unsigned short* gp = W1s + ((size_t)kt * 1024 + (size_t)(i * 512 + t)) * 8;
            unsigned short* lp = &Bs[buf][(i * 512 + wave * 64) * 8];
            __builtin_amdgcn_global_load_lds(
                (const __attribute__((address_space(1))) unsigned int*)gp,
                (__attribute__((address_space(3))) unsigned int*)lp, 16, 0, 0);
        }
    };
    auto writeA = [&](int buf) {
        #pragma unroll
        for (int i = 0; i < 4; ++i) {
            int quad = i * 512 + t;
            int row = quad >> 4, kq = quad & 15;
            __hip_bfloat162 lo2 = __float22bfloat162_rn(make_float2(areg[i].x, areg[i].y));
            __hip_bfloat162 hi2 = __float22bfloat162_rn(make_float2(areg[i].z, areg[i].w));
            unsigned int ulo, uhi;
            __builtin_memcpy(&ulo, &lo2, 4);
            __builtin_memcpy(&uhi, &hi2, 4);
            unsigned long long pk = ((unsigned long long)uhi << 32) | (unsigned long long)ulo;
            int us = row * 64 + ((kq * 4) ^ ((row & 7) << 3));
            *(unsigned long long*)(&As[buf][us]) = pk;
        }
    };
    auto compute = [&](int buf) {
        short8_t af[2][2], bfr[2][4];
        #pragma unroll
        for (int ks = 0; ks < 2; ++ks) {
            int g = ks * 4 + u;
            #pragma unroll
            for (int mi = 0; mi < 2; ++mi) {
                int row = wm * 32 + mi * 16 + r;
                int us = row * 64 + ((g * 8) ^ ((row & 7) << 3));
                af[ks][mi] = *(const short8_t*)(&As[buf][us]);
            }
            #pragma unroll
            for (int ni = 0; ni < 4; ++ni) {
                int c = wn * 64 + ni * 16 + r;
                bfr[ks][ni] = *(const short8_t*)(&Bs[buf][g * 1024 + c * 8]);
            }
        }
        #pragma unroll
        for (int ks = 0; ks < 2; ++ks)
            #pragma unroll
            for (int mi = 0; mi < 2; ++mi)
                #pragma unroll
                for (int ni = 0; ni < 4; ++ni)
                    acc[mi][ni] = __builtin_amdgcn_mfma_f32_16x16x32_bf16(af[ks][mi], bfr[ks][ni], acc[mi][ni], 0, 0, 0);
    };

    // prologue: stage tile 0
    issueA(0);
    issueB(0, 0);
    writeA(0);                 // auto vmcnt wait on A loads
    __syncthreads();           // drains B gload_lds + makes A writes visible

    int cur = 0;
    for (int kt = 0; kt < KT1; ++kt) {
        int nxt = cur ^ 1;
        if (kt + 1 < KT1) { issueA(kt + 1); issueB(kt + 1, nxt); }
        compute(cur);
        if (kt + 1 < KT1) writeA(nxt);   // A[nxt] readers retired before previous barrier
        __syncthreads();                 // one barrier/iter
        cur = nxt;
    }

    // epilogue: C layout col=lane&15, row=(lane>>4)*4+reg; pre-scale by dinv[row]
    #pragma unroll
    for (int mi = 0; mi < 2; ++mi) {
        #pragma unroll
        for (int reg = 0; reg < 4; ++reg) {
            int grow = rowBase + wm * 32 + mi * 16 + u * 4 + reg;
            if (grow < M) {
                float dv = dinv[grow];
                #pragma unroll
                for (int ni = 0; ni < 4; ++ni) {
                    int gcol = wn * 64 + ni * 16 + r;
                    h[(size_t)grow * HID + gcol] = f2bf(dv * acc[mi][ni][reg]);
                }
            }
        }
    }
}

// ---------------- Aggregation 1 + bias + relu + @W2 fused ----------------
// h is pre-scaled by dinv[src]; csr includes self-loop -> branchless sum.
// one wave per node; lane = (row-group g = lane>>4) x (feature-octet fr = lane&15)
__global__ __launch_bounds__(256) void agg1(const unsigned short* __restrict__ h,
                                            const int* __restrict__ ptr,
                                            const int* __restrict__ deg,
                                            const int* __restrict__ csr,
                                            const float* __restrict__ dinv,
                                            const float* __restrict__ b1,
                                            const float* __restrict__ W2,
                                            float* __restrict__ h2s, int n) {
    __shared__ float W2s[HID * NCLS];
    for (int i = threadIdx.x; i < HID * NCLS; i += 256) W2s[i] = W2[i];
    __syncthreads();
    int wave = threadIdx.x >> 6, lane = threadIdx.x & 63;
    int v = blockIdx.x * 4 + wave;
    if (v >= n) return;
    const int fr = lane & 15, g = lane >> 4;
    int p0 = ptr[v];
    int total = deg[v];                 // in-edges + self (all in csr)
    float acc[8] = {};
    #pragma unroll 8
    for (int j = g; j < total; j += 4) {
        int s = csr[p0 + j];
        uint4 q = *(const uint4*)(h + (size_t)s * HID + fr * 8);
        unsigned int w[4] = {q.x, q.y, q.z, q.w};
        #pragma unroll
        for (int p = 0; p < 4; ++p) {
            acc[p * 2 + 0] += bf2f((unsigned short)(w[p] & 0xffffu));
            acc[p * 2 + 1] += bf2f((unsigned short)(w[p] >> 16));
        }
    }
    // combine the 4 row-groups
    #pragma unroll
    for (int e = 0; e < 8; ++e) {
        acc[e] += __shfl_xor(acc[e], 16, 64);
        acc[e] += __shfl_xor(acc[e], 32, 64);
    }
    float dv = dinv[v];
    // bias + relu + W2 projection (each lane: features fr*8..fr*8+7)
    float p[NCLS];
    #pragma unroll
    for (int c = 0; c < NCLS; ++c) p[c] = 0.f;
    #pragma unroll
    for (int e = 0; e < 8; ++e) {
        int f = fr * 8 + e;
        float val = fmaxf(dv * acc[e] + b1[f], 0.f);
        #pragma unroll
        for (int c = 0; c < NCLS; ++c) p[c] += val * W2s[f * NCLS + c];
    }
    #pragma unroll
    for (int off = 8; off >= 1; off >>= 1)
        #pragma unroll
        for (int c = 0; c < NCLS; ++c)
            p[c] += __shfl_xor(p[c], off, 64);
    if (lane == 0) {
        #pragma unroll
        for (int c = 0; c < NCLS; ++c) h2s[(size_t)v * 8 + c] = dv * p[c];  // pre-scaled
        h2s[(size_t)v * 8 + 7] = 0.f;
    }
}

// ---------------- Aggregation 2 + bias ----------------
// h2s pre-scaled by dinv[src]; csr includes self. 32 lanes/node: 4 edge-groups
// x 8 feature-lanes; 2 nodes per wave.
__global__ __launch_bounds__(256) void agg2(const float* __restrict__ h2s,
                                            const int* __restrict__ ptr,
                                            const int* __restrict__ deg,
                                            const int* __restrict__ csr,
                                            const float* __restrict__ dinv,
                                            const float* __restrict__ b2,
                                            float* __restrict__ out, int n) {
    int wave = threadIdx.x >> 6, lane = threadIdx.x & 63;
    int half = lane >> 5;
    int c = lane & 7, g = (lane >> 3) & 3;
    int v = blockIdx.x * 8 + wave * 2 + half;
    if (v >= n) return;
    int p0 = ptr[v], total = deg[v];
    float acc = 0.f;
    #pragma unroll 8
    for (int j = g; j < total; j += 4) {
        int s = csr[p0 + j];
        acc += h2s[(size_t)s * 8 + c];
    }
    acc += __shfl_xor(acc, 8, 64);
    acc += __shfl_xor(acc, 16, 64);
    if (g == 0 && c < NCLS) out[(size_t)v * NCLS + c] = dinv[v] * acc + b2[c];
}

extern "C" void kernel_launch(void* const* d_in, const int* in_sizes, int n_in,
                              void* d_out, int out_size, void* d_ws, size_t ws_size,
                              hipStream_t stream) {
    const float* x  = (const float*)d_in[0];
    const int*   ei = (const int*)d_in[1];    // int64 in reference but JAX x64-off => int32
    const float* W1 = (const float*)d_in[2];
    const float* b1 = (const float*)d_in[3];
    const float* W2 = (const float*)d_in[4];
    const float* b2 = (const float*)d_in[5];
    float* out = (float*)d_out;

    const int N = NNODES;
    const int E = in_sizes[1] / 2;
    const int* src = ei;
    const int* dst = ei + E;
    const int NB = (N + 255) / 256;           // scan blocks (196 <= 256)

    char* ws = (char*)d_ws;
    size_t off = 0;
    auto alloc = [&](size_t bytes) {
        void* p = ws + off;
        off += (bytes + 255) & ~(size_t)255;
        return p;
    };
    int*   deg    = (int*)alloc((size_t)N * 4);
    float* dinv   = (float*)alloc((size_t)N * 4);
    int*   ptr    = (int*)alloc((size_t)N * 4);
    int*   cursor = (int*)alloc((size_t)N * 4);
    int*   blksum = (int*)alloc((size_t)NB * 4);
    int*   csr    = (int*)alloc((size_t)(E + N) * 4);
    unsigned short* W1s = (unsigned short*)alloc((size_t)KT1 * 1024 * 8 * 2);
    unsigned short* h   = (unsigned short*)alloc((size_t)N * HID * 2);
    float* h2s    = (float*)alloc((size_t)N * 8 * 4);

    init_deg<<<NB, 256, 0, stream>>>(deg, N);
    count_deg4<<<(E / 4 + 255) / 256, 256, 0, stream>>>(dst, E, deg);
    calc_dinv<<<NB, 256, 0, stream>>>(deg, dinv, N);
    scan_part<<<NB, 256, 0, stream>>>(deg, blksum, N);
    scan_block<<<1, 256, 0, stream>>>(blksum, NB);
    scan_apply<<<NB, 256, 0, stream>>>(deg, blksum, ptr, cursor, N);
    fill_csr4<<<(E / 4 + 255) / 256, 256, 0, stream>>>(src, dst, E, cursor, csr);
    fill_self<<<NB, 256, 0, stream>>>(cursor, csr, N);
    prep_w1<<<(KT1 * 1024 + 255) / 256, 256, 0, stream>>>(W1, W1s);
    gemm1<<<(N + BM - 1) / BM, 512, 0, stream>>>(x, W1s, dinv, h, N);
    agg1<<<(N + 3) / 4, 256, 0, stream>>>(h, ptr, deg, csr, dinv, b1, W2, h2s, N);
    agg2<<<(N + 7) / 8, 256, 0, stream>>>(h2s, ptr, deg, csr, dinv, b2, out, N);
}

// Round 8
// 394.926 us; speedup vs baseline: 1.4135x; 1.0248x over previous
//
#include <hip/hip_runtime.h>
#include <hip/hip_bf16.h>

typedef __attribute__((ext_vector_type(8))) short short8_t;
typedef __attribute__((ext_vector_type(4))) float f32x4;
typedef float f32x4u __attribute__((ext_vector_type(4), aligned(4)));  // 4B-aligned vector load

#define NNODES 50000
#define FIN 1433
#define HID 128
#define NCLS 7
#define KT1 23          // ceil(1433/64)
#define BK 64
#define BM 128

static __device__ __forceinline__ unsigned short f2bf(float f) {
    union { float f; unsigned int u; } v; v.f = f;
    unsigned int u = v.u;
    u += 0x7FFFu + ((u >> 16) & 1u);   // round-to-nearest-even
    return (unsigned short)(u >> 16);
}
static __device__ __forceinline__ float bf2f(unsigned short b) {
    union { unsigned int u; float f; } v; v.u = ((unsigned int)b) << 16; return v.f;
}

// ---------------- degree / norm ----------------
__global__ void init_deg(int* deg, int n) {
    int i = blockIdx.x * blockDim.x + threadIdx.x;
    if (i < n) deg[i] = 1;              // self loop
}

// 4 edges per thread, int4 coalesced
__global__ void count_deg4(const int* __restrict__ dst, int E, int* deg) {
    int q = blockIdx.x * 256 + threadIdx.x;
    int i = q * 4;
    if (i + 3 < E) {
        int4 d = *(const int4*)(dst + i);
        atomicAdd(&deg[d.x], 1);
        atomicAdd(&deg[d.y], 1);
        atomicAdd(&deg[d.z], 1);
        atomicAdd(&deg[d.w], 1);
    } else if (i < E) {
        for (int e = i; e < E; ++e) atomicAdd(&deg[dst[e]], 1);
    }
}

__global__ void calc_dinv(const int* __restrict__ deg, float* dinv, int n) {
    int i = blockIdx.x * blockDim.x + threadIdx.x;
    if (i < n) dinv[i] = rsqrtf((float)deg[i]);
}

// ---------------- CSR build (self-loops INCLUDED in csr) ----------------
// 3-kernel parallel exclusive scan of deg -> ptr/cursor
__global__ void scan_part(const int* __restrict__ deg, int* __restrict__ blksum, int n) {
    __shared__ int ws[4];
    int i = blockIdx.x * 256 + threadIdx.x;
    int wave = threadIdx.x >> 6, lane = threadIdx.x & 63;
    int s = (i < n) ? deg[i] : 0;
    #pragma unroll
    for (int off = 1; off < 64; off <<= 1) s += __shfl_xor(s, off, 64);
    if (lane == 0) ws[wave] = s;
    __syncthreads();
    if (threadIdx.x == 0) blksum[blockIdx.x] = ws[0] + ws[1] + ws[2] + ws[3];
}

__global__ void scan_block(int* blksum, int nb) {   // one block, nb <= 256
    __shared__ int tmp[256];
    int t = threadIdx.x;
    int v = (t < nb) ? blksum[t] : 0;
    tmp[t] = v;
    __syncthreads();
    #pragma unroll
    for (int off = 1; off < 256; off <<= 1) {
        int u = (t >= off) ? tmp[t - off] : 0;
        __syncthreads();
        tmp[t] += u;
        __syncthreads();
    }
    if (t < nb) blksum[t] = tmp[t] - v;             // exclusive
}

__global__ void scan_apply(const int* __restrict__ deg, const int* __restrict__ blksum,
                           int* __restrict__ ptr, int* __restrict__ cursor, int n) {
    __shared__ int tmp[256];
    int t = threadIdx.x;
    int i = blockIdx.x * 256 + t;
    int v = (i < n) ? deg[i] : 0;
    tmp[t] = v;
    __syncthreads();
    #pragma unroll
    for (int off = 1; off < 256; off <<= 1) {
        int u = (t >= off) ? tmp[t - off] : 0;
        __syncthreads();
        tmp[t] += u;
        __syncthreads();
    }
    if (i < n) {
        int excl = blksum[blockIdx.x] + tmp[t] - v;
        ptr[i] = excl;
        cursor[i] = excl;
    }
}

// 4 edges per thread, int4 coalesced reads of src+dst
__global__ void fill_csr4(const int* __restrict__ src, const int* __restrict__ dst,
                          int E, int* cursor, int* csr) {
    int q = blockIdx.x * 256 + threadIdx.x;
    int i = q * 4;
    if (i + 3 < E) {
        int4 d = *(const int4*)(dst + i);
        int4 s = *(const int4*)(src + i);
        csr[atomicAdd(&cursor[d.x], 1)] = s.x;
        csr[atomicAdd(&cursor[d.y], 1)] = s.y;
        csr[atomicAdd(&cursor[d.z], 1)] = s.z;
        csr[atomicAdd(&cursor[d.w], 1)] = s.w;
    } else if (i < E) {
        for (int e = i; e < E; ++e)
            csr[atomicAdd(&cursor[dst[e]], 1)] = src[e];
    }
}

__global__ void fill_self(int* cursor, int* csr, int n) {
    int v = blockIdx.x * blockDim.x + threadIdx.x;
    if (v < n) {
        int pos = atomicAdd(&cursor[v], 1);
        csr[pos] = v;
    }
}

// ---------------- W1 pack: W1[FIN][HID] f32 -> W1s[KT1][1024 segs][8 bf16]
// seg = g*128 + c  (g = k-octet within BK tile, c = output col); LDS-tile order.
__global__ void prep_w1(const float* __restrict__ W1, unsigned short* __restrict__ W1s) {
    int tid = blockIdx.x * 256 + threadIdx.x;
    if (tid >= KT1 * 1024) return;
    int kt = tid >> 10, seg = tid & 1023;
    int c = seg & 127, g = seg >> 7;
    int kb = kt * BK + g * 8;
    unsigned int w[4];
    #pragma unroll
    for (int p = 0; p < 4; ++p) {
        int k0 = kb + p * 2, k1 = kb + p * 2 + 1;
        unsigned short lo = (k0 < FIN) ? f2bf(W1[(size_t)k0 * HID + c]) : (unsigned short)0;
        unsigned short hi = (k1 < FIN) ? f2bf(W1[(size_t)k1 * HID + c]) : (unsigned short)0;
        w[p] = (unsigned int)lo | ((unsigned int)hi << 16);
    }
    uint4* dstp = (uint4*)(W1s + (size_t)tid * 8);
    uint4 val; val.x = w[0]; val.y = w[1]; val.z = w[2]; val.w = w[3];
    *dstp = val;
}

// ---------------- GEMM1: h'[M][128] (bf16) = dinv[r] * (x[M][1433] @ W1) ----
// BM=128, BK=64, 512 threads / 8 waves. Two-tile-deep pipeline with COUNTED
// vmcnt (T3/T4): A reg-staged 1 ahead, B gload_lds 2 ahead into 3-deep ring.
// Issue order per iter (writeA(t+1) -> issueA(t+2) -> issueB(t+2)) + in-order
// vmcnt retirement makes s_waitcnt vmcnt(6) retire B(t+1) while keeping the
// 6 loads of tile t+2 in flight across the barrier.
__global__ __launch_bounds__(512, 4) void gemm1(const float* __restrict__ x,
                                                const unsigned short* __restrict__ W1s,
                                                const float* __restrict__ dinv,
                                                unsigned short* __restrict__ h, int M) {
    // A: [row 128][(g*8) ^ ((row&7)<<3) ..+7] ushorts (XOR-swizzled, 16KB/buf x2)
    // B: [g 8][c 128][8] ushorts (linear, gload_lds order, 16KB/buf x3)
    __shared__ unsigned short As[2][8192];
    __shared__ unsigned short Bs[3][8192];
    const int t = threadIdx.x;
    const int wave = t >> 6, lane = t & 63;
    const int wm = wave >> 1, wn = wave & 1;
    const int r = lane & 15, u = lane >> 4;
    const int rowBase = blockIdx.x * BM;
    f32x4 acc[2][4] = {};

    float4 areg[4];

    auto issueA = [&](int kt) {
        int k0 = kt * BK;
        #pragma unroll
        for (int i = 0; i < 4; ++i) {
            int quad = i * 512 + t;
            int row = quad >> 4, kq = quad & 15;
            int gr = rowBase + row;
            int gk = k0 + kq * 4;
            if (gr < M && gk + 3 < FIN) {
                f32x4u v = *(const f32x4u*)(x + (size_t)gr * FIN + gk);
                areg[i].x = v.x; areg[i].y = v.y; areg[i].z = v.z; areg[i].w = v.w;
            } else {
                areg[i].x = (gr < M && gk + 0 < FIN) ? x[(size_t)gr * FIN + gk + 0] : 0.f;
                areg[i].y = (gr < M && gk + 1 < FIN) ? x[(size_t)gr * FIN + gk + 1] : 0.f;
                areg[i].z = (gr < M && gk + 2 < FIN) ? x[(size_t)gr * FIN + gk + 2] : 0.f;
                areg[i].w = (gr < M && gk + 3 < FIN) ? x[(size_t)gr * FIN + gk + 3] : 0.f;
            }
        }
    };
    auto issueB = [&](int kt, int buf) {
        #pragma unroll
        for (int i = 0; i < 2; ++i) {
            const unsigned short* gp = W1s + ((size_t)kt * 1024 + (size_t)(i * 512 + t)) * 8;
            unsigned short* lp = &Bs[buf][(i * 512 + wave * 64) * 8];
            __builtin_amdgcn_global_load_lds(
                (const __attribute__((address_space(1))) unsigned int*)gp,
                (__attribute__((address_space(3))) unsigned int*)lp, 16, 0, 0);
        }
    };
    auto writeA = [&](int buf) {
        #pragma unroll
        for (int i = 0; i < 4; ++i) {
            int quad = i * 512 + t;
            int row = quad >> 4, kq = quad & 15;
            __hip_bfloat162 lo2 = __float22bfloat162_rn(make_float2(areg[i].x, areg[i].y));
            __hip_bfloat162 hi2 = __float22bfloat162_rn(make_float2(areg[i].z, areg[i].w));
            unsigned int ulo, uhi;
            __builtin_memcpy(&ulo, &lo2, 4);
            __builtin_memcpy(&uhi, &hi2, 4);
            unsigned long long pk = ((unsigned long long)uhi << 32) | (unsigned long long)ulo;
            int us = row * 64 + ((kq * 4) ^ ((row & 7) << 3));
            *(unsigned long long*)(&As[buf][us]) = pk;
        }
    };
    auto compute = [&](int abuf, int bbuf) {
        short8_t af[2][2], bfr[2][4];
        #pragma unroll
        for (int ks = 0; ks < 2; ++ks) {
            int g = ks * 4 + u;
            #pragma unroll
            for (int mi = 0; mi < 2; ++mi) {
                int row = wm * 32 + mi * 16 + r;
                int us = row * 64 + ((g * 8) ^ ((row & 7) << 3));
                af[ks][mi] = *(const short8_t*)(&As[abuf][us]);
            }
            #pragma unroll
            for (int ni = 0; ni < 4; ++ni) {
                int c = wn * 64 + ni * 16 + r;
                bfr[ks][ni] = *(const short8_t*)(&Bs[bbuf][g * 1024 + c * 8]);
            }
        }
        #pragma unroll
        for (int ks = 0; ks < 2; ++ks)
            #pragma unroll
            for (int mi = 0; mi < 2; ++mi)
                #pragma unroll
                for (int ni = 0; ni < 4; ++ni)
                    acc[mi][ni] = __builtin_amdgcn_mfma_f32_16x16x32_bf16(af[ks][mi], bfr[ks][ni], acc[mi][ni], 0, 0, 0);
    };

    // prologue: tile 0 staged, tile 1 in flight
    issueA(0); issueB(0, 0);
    writeA(0);                       // data-dep waits A(0); B(0) may remain in flight
    issueA(1); issueB(1, 1);
    asm volatile("s_waitcnt vmcnt(6) lgkmcnt(0)" ::: "memory");  // B(0) done; A(1)+B(1) in flight
    __builtin_amdgcn_sched_barrier(0);
    __builtin_amdgcn_s_barrier();
    __builtin_amdgcn_sched_barrier(0);

    // steady state: t = 0 .. KT1-3
    for (int kt = 0; kt < KT1 - 2; ++kt) {
        compute(kt & 1, kt % 3);
        writeA((kt + 1) & 1);        // waits A(t+1) (issued before B(t+1))
        issueA(kt + 2);
        issueB(kt + 2, (kt + 2) % 3);
        asm volatile("s_waitcnt vmcnt(6) lgkmcnt(0)" ::: "memory");  // B(t+1) done; tile t+2 in flight
        __builtin_amdgcn_sched_barrier(0);
        __builtin_amdgcn_s_barrier();
        __builtin_amdgcn_sched_barrier(0);
    }
    // t = KT1-2: nothing new to issue; full drain
    {
        const int kt = KT1 - 2;
        compute(kt & 1, kt % 3);
        writeA((kt + 1) & 1);
        __syncthreads();
    }
    // t = KT1-1
    compute((KT1 - 1) & 1, (KT1 - 1) % 3);

    // epilogue: C layout col=lane&15, row=(lane>>4)*4+reg; pre-scale by dinv[row]
    #pragma unroll
    for (int mi = 0; mi < 2; ++mi) {
        #pragma unroll
        for (int reg = 0; reg < 4; ++reg) {
            int grow = rowBase + wm * 32 + mi * 16 + u * 4 + reg;
            if (grow < M) {
                float dv = dinv[grow];
                #pragma unroll
                for (int ni = 0; ni < 4; ++ni) {
                    int gcol = wn * 64 + ni * 16 + r;
                    h[(size_t)grow * HID + gcol] = f2bf(dv * acc[mi][ni][reg]);
                }
            }
        }
    }
}

// ---------------- Aggregation 1 + bias + relu + @W2 fused ----------------
// h is pre-scaled by dinv[src]; csr includes self-loop -> branchless sum.
// one wave per node; lane = (row-group g = lane>>4) x (feature-octet fr = lane&15)
__global__ __launch_bounds__(256) void agg1(const unsigned short* __restrict__ h,
                                            const int* __restrict__ ptr,
                                            const int* __restrict__ deg,
                                            const int* __restrict__ csr,
                                            const float* __restrict__ dinv,
                                            const float* __restrict__ b1,
                                            const float* __restrict__ W2,
                                            float* __restrict__ h2s, int n) {
    __shared__ float W2s[HID * NCLS];
    for (int i = threadIdx.x; i < HID * NCLS; i += 256) W2s[i] = W2[i];
    __syncthreads();
    int wave = threadIdx.x >> 6, lane = threadIdx.x & 63;
    int v = blockIdx.x * 4 + wave;
    if (v >= n) return;
    const int fr = lane & 15, g = lane >> 4;
    int p0 = ptr[v];
    int total = deg[v];                 // in-edges + self (all in csr)
    float acc[8] = {};
    #pragma unroll 8
    for (int j = g; j < total; j += 4) {
        int s = csr[p0 + j];
        uint4 q = *(const uint4*)(h + (size_t)s * HID + fr * 8);
        unsigned int w[4] = {q.x, q.y, q.z, q.w};
        #pragma unroll
        for (int p = 0; p < 4; ++p) {
            acc[p * 2 + 0] += bf2f((unsigned short)(w[p] & 0xffffu));
            acc[p * 2 + 1] += bf2f((unsigned short)(w[p] >> 16));
        }
    }
    // combine the 4 row-groups
    #pragma unroll
    for (int e = 0; e < 8; ++e) {
        acc[e] += __shfl_xor(acc[e], 16, 64);
        acc[e] += __shfl_xor(acc[e], 32, 64);
    }
    float dv = dinv[v];
    // bias + relu + W2 projection (each lane: features fr*8..fr*8+7)
    float p[NCLS];
    #pragma unroll
    for (int c = 0; c < NCLS; ++c) p[c] = 0.f;
    #pragma unroll
    for (int e = 0; e < 8; ++e) {
        int f = fr * 8 + e;
        float val = fmaxf(dv * acc[e] + b1[f], 0.f);
        #pragma unroll
        for (int c = 0; c < NCLS; ++c) p[c] += val * W2s[f * NCLS + c];
    }
    #pragma unroll
    for (int off = 8; off >= 1; off >>= 1)
        #pragma unroll
        for (int c = 0; c < NCLS; ++c)
            p[c] += __shfl_xor(p[c], off, 64);
    if (lane == 0) {
        #pragma unroll
        for (int c = 0; c < NCLS; ++c) h2s[(size_t)v * 8 + c] = dv * p[c];  // pre-scaled
        h2s[(size_t)v * 8 + 7] = 0.f;
    }
}

// ---------------- Aggregation 2 + bias ----------------
// h2s pre-scaled by dinv[src]; csr includes self. 32 lanes/node: 4 edge-groups
// x 8 feature-lanes; 2 nodes per wave.
__global__ __launch_bounds__(256) void agg2(const float* __restrict__ h2s,
                                            const int* __restrict__ ptr,
                                            const int* __restrict__ deg,
                                            const int* __restrict__ csr,
                                            const float* __restrict__ dinv,
                                            const float* __restrict__ b2,
                                            float* __restrict__ out, int n) {
    int wave = threadIdx.x >> 6, lane = threadIdx.x & 63;
    int half = lane >> 5;
    int c = lane & 7, g = (lane >> 3) & 3;
    int v = blockIdx.x * 8 + wave * 2 + half;
    if (v >= n) return;
    int p0 = ptr[v], total = deg[v];
    float acc = 0.f;
    #pragma unroll 8
    for (int j = g; j < total; j += 4) {
        int s = csr[p0 + j];
        acc += h2s[(size_t)s * 8 + c];
    }
    acc += __shfl_xor(acc, 8, 64);
    acc += __shfl_xor(acc, 16, 64);
    if (g == 0 && c < NCLS) out[(size_t)v * NCLS + c] = dinv[v] * acc + b2[c];
}

extern "C" void kernel_launch(void* const* d_in, const int* in_sizes, int n_in,
                              void* d_out, int out_size, void* d_ws, size_t ws_size,
                              hipStream_t stream) {
    const float* x  = (const float*)d_in[0];
    const int*   ei = (const int*)d_in[1];    // int64 in reference but JAX x64-off => int32
    const float* W1 = (const float*)d_in[2];
    const float* b1 = (const float*)d_in[3];
    const float* W2 = (const float*)d_in[4];
    const float* b2 = (const float*)d_in[5];
    float* out = (float*)d_out;

    const int N = NNODES;
    const int E = in_sizes[1] / 2;
    const int* src = ei;
    const int* dst = ei + E;
    const int NB = (N + 255) / 256;           // scan blocks (196 <= 256)

    char* ws = (char*)d_ws;
    size_t off = 0;
    auto alloc = [&](size_t bytes) {
        void* p = ws + off;
        off += (bytes + 255) & ~(size_t)255;
        return p;
    };
    int*   deg    = (int*)alloc((size_t)N * 4);
    float* dinv   = (float*)alloc((size_t)N * 4);
    int*   ptr    = (int*)alloc((size_t)N * 4);
    int*   cursor = (int*)alloc((size_t)N * 4);
    int*   blksum = (int*)alloc((size_t)NB * 4);
    int*   csr    = (int*)alloc((size_t)(E + N) * 4);
    unsigned short* W1s = (unsigned short*)alloc((size_t)KT1 * 1024 * 8 * 2);
    unsigned short* h   = (unsigned short*)alloc((size_t)N * HID * 2);
    float* h2s    = (float*)alloc((size_t)N * 8 * 4);

    init_deg<<<NB, 256, 0, stream>>>(deg, N);
    count_deg4<<<(E / 4 + 255) / 256, 256, 0, stream>>>(dst, E, deg);
    calc_dinv<<<NB, 256, 0, stream>>>(deg, dinv, N);
    scan_part<<<NB, 256, 0, stream>>>(deg, blksum, N);
    scan_block<<<1, 256, 0, stream>>>(blksum, NB);
    scan_apply<<<NB, 256, 0, stream>>>(deg, blksum, ptr, cursor, N);
    fill_csr4<<<(E / 4 + 255) / 256, 256, 0, stream>>>(src, dst, E, cursor, csr);
    fill_self<<<NB, 256, 0, stream>>>(cursor, csr, N);
    prep_w1<<<(KT1 * 1024 + 255) / 256, 256, 0, stream>>>(W1, W1s);
    gemm1<<<(N + BM - 1) / BM, 512, 0, stream>>>(x, W1s, dinv, h, N);
    agg1<<<(N + 3) / 4, 256, 0, stream>>>(h, ptr, deg, csr, dinv, b1, W2, h2s, N);
    agg2<<<(N + 7) / 8, 256, 0, stream>>>(h2s, ptr, deg, csr, dinv, b2, out, N);
}

// Round 9
// 391.910 us; speedup vs baseline: 1.4244x; 1.0077x over previous
//
#include <hip/hip_runtime.h>
#include <hip/hip_bf16.h>

typedef __attribute__((ext_vector_type(8))) short short8_t;
typedef __attribute__((ext_vector_type(4))) float f32x4;
typedef float f32x4u __attribute__((ext_vector_type(4), aligned(4)));  // 4B-aligned vector load

#define NNODES 50000
#define FIN 1433
#define HID 128
#define NCLS 7
#define KT1 23          // ceil(1433/64)
#define BK 64
#define BM 128

static __device__ __forceinline__ unsigned short f2bf(float f) {
    union { float f; unsigned int u; } v; v.f = f;
    unsigned int u = v.u;
    u += 0x7FFFu + ((u >> 16) & 1u);   // round-to-nearest-even
    return (unsigned short)(u >> 16);
}
static __device__ __forceinline__ float bf2f(unsigned short b) {
    union { unsigned int u; float f; } v; v.u = ((unsigned int)b) << 16; return v.f;
}

// ---------------- degree / norm ----------------
__global__ void init_deg(int* deg, int n) {
    int i = blockIdx.x * blockDim.x + threadIdx.x;
    if (i < n) deg[i] = 1;              // self loop
}

// 4 edges per thread, int4 coalesced
__global__ void count_deg4(const int* __restrict__ dst, int E, int* deg) {
    int q = blockIdx.x * 256 + threadIdx.x;
    int i = q * 4;
    if (i + 3 < E) {
        int4 d = *(const int4*)(dst + i);
        atomicAdd(&deg[d.x], 1);
        atomicAdd(&deg[d.y], 1);
        atomicAdd(&deg[d.z], 1);
        atomicAdd(&deg[d.w], 1);
    } else if (i < E) {
        for (int e = i; e < E; ++e) atomicAdd(&deg[dst[e]], 1);
    }
}

// ---------------- CSR build (self-loops included, written by scan_apply) ----
__global__ void scan_part(const int* __restrict__ deg, int* __restrict__ blksum, int n) {
    __shared__ int ws[4];
    int i = blockIdx.x * 256 + threadIdx.x;
    int wave = threadIdx.x >> 6, lane = threadIdx.x & 63;
    int s = (i < n) ? deg[i] : 0;
    #pragma unroll
    for (int off = 1; off < 64; off <<= 1) s += __shfl_xor(s, off, 64);
    if (lane == 0) ws[wave] = s;
    __syncthreads();
    if (threadIdx.x == 0) blksum[blockIdx.x] = ws[0] + ws[1] + ws[2] + ws[3];
}

__global__ void scan_block(int* blksum, int nb) {   // one block, nb <= 256
    __shared__ int tmp[256];
    int t = threadIdx.x;
    int v = (t < nb) ? blksum[t] : 0;
    tmp[t] = v;
    __syncthreads();
    #pragma unroll
    for (int off = 1; off < 256; off <<= 1) {
        int u = (t >= off) ? tmp[t - off] : 0;
        __syncthreads();
        tmp[t] += u;
        __syncthreads();
    }
    if (t < nb) blksum[t] = tmp[t] - v;             // exclusive
}

// scan_apply also: dinv = rsqrt(deg), csr[ptr]=self, cursor=ptr+1
__global__ void scan_apply(const int* __restrict__ deg, const int* __restrict__ blksum,
                           int* __restrict__ ptr, int* __restrict__ cursor,
                           float* __restrict__ dinv, int* __restrict__ csr, int n) {
    __shared__ int tmp[256];
    int t = threadIdx.x;
    int i = blockIdx.x * 256 + t;
    int v = (i < n) ? deg[i] : 0;
    tmp[t] = v;
    __syncthreads();
    #pragma unroll
    for (int off = 1; off < 256; off <<= 1) {
        int u = (t >= off) ? tmp[t - off] : 0;
        __syncthreads();
        tmp[t] += u;
        __syncthreads();
    }
    if (i < n) {
        int excl = blksum[blockIdx.x] + tmp[t] - v;
        ptr[i] = excl;
        csr[excl] = i;                  // self loop first (list order irrelevant)
        cursor[i] = excl + 1;
        dinv[i] = rsqrtf((float)v);
    }
}

// 4 edges per thread, int4 coalesced reads of src+dst
__global__ void fill_csr4(const int* __restrict__ src, const int* __restrict__ dst,
                          int E, int* cursor, int* csr) {
    int q = blockIdx.x * 256 + threadIdx.x;
    int i = q * 4;
    if (i + 3 < E) {
        int4 d = *(const int4*)(dst + i);
        int4 s = *(const int4*)(src + i);
        csr[atomicAdd(&cursor[d.x], 1)] = s.x;
        csr[atomicAdd(&cursor[d.y], 1)] = s.y;
        csr[atomicAdd(&cursor[d.z], 1)] = s.z;
        csr[atomicAdd(&cursor[d.w], 1)] = s.w;
    } else if (i < E) {
        for (int e = i; e < E; ++e)
            csr[atomicAdd(&cursor[dst[e]], 1)] = src[e];
    }
}

// ---------------- W1 pack: W1[FIN][HID] f32 -> W1s[KT1][1024 segs][8 bf16]
__global__ void prep_w1(const float* __restrict__ W1, unsigned short* __restrict__ W1s) {
    int tid = blockIdx.x * 256 + threadIdx.x;
    if (tid >= KT1 * 1024) return;
    int kt = tid >> 10, seg = tid & 1023;
    int c = seg & 127, g = seg >> 7;
    int kb = kt * BK + g * 8;
    unsigned int w[4];
    #pragma unroll
    for (int p = 0; p < 4; ++p) {
        int k0 = kb + p * 2, k1 = kb + p * 2 + 1;
        unsigned short lo = (k0 < FIN) ? f2bf(W1[(size_t)k0 * HID + c]) : (unsigned short)0;
        unsigned short hi = (k1 < FIN) ? f2bf(W1[(size_t)k1 * HID + c]) : (unsigned short)0;
        w[p] = (unsigned int)lo | ((unsigned int)hi << 16);
    }
    uint4* dstp = (uint4*)(W1s + (size_t)tid * 8);
    uint4 val; val.x = w[0]; val.y = w[1]; val.z = w[2]; val.w = w[3];
    *dstp = val;
}

// ---------------- GEMM1: h'[M][128] (bf16) = dinv[r] * (x[M][1433] @ W1) ----
// BM=128, BK=64, 512 threads / 8 waves. Counted-vmcnt 2-deep pipeline.
// A loads are NON-TEMPORAL: x has zero reuse; keeping it out of L2 leaves
// W1s L2-resident per XCD (kills the 144MB B re-fetch stream).
__global__ __launch_bounds__(512, 4) void gemm1(const float* __restrict__ x,
                                                const unsigned short* __restrict__ W1s,
                                                const float* __restrict__ dinv,
                                                unsigned short* __restrict__ h, int M) {
    __shared__ unsigned short As[2][8192];
    __shared__ unsigned short Bs[3][8192];
    const int t = threadIdx.x;
    const int wave = t >> 6, lane = t & 63;
    const int wm = wave >> 1, wn = wave & 1;
    const int r = lane & 15, u = lane >> 4;
    const int rowBase = blockIdx.x * BM;
    f32x4 acc[2][4] = {};

    float4 areg[4];

    auto issueA = [&](int kt) {
        int k0 = kt * BK;
        #pragma unroll
        for (int i = 0; i < 4; ++i) {
            int quad = i * 512 + t;
            int row = quad >> 4, kq = quad & 15;
            int gr = rowBase + row;
            int gk = k0 + kq * 4;
            if (gr < M && gk + 3 < FIN) {
                f32x4u v = __builtin_nontemporal_load((const f32x4u*)(x + (size_t)gr * FIN + gk));
                areg[i].x = v.x; areg[i].y = v.y; areg[i].z = v.z; areg[i].w = v.w;
            } else {
                areg[i].x = (gr < M && gk + 0 < FIN) ? x[(size_t)gr * FIN + gk + 0] : 0.f;
                areg[i].y = (gr < M && gk + 1 < FIN) ? x[(size_t)gr * FIN + gk + 1] : 0.f;
                areg[i].z = (gr < M && gk + 2 < FIN) ? x[(size_t)gr * FIN + gk + 2] : 0.f;
                areg[i].w = (gr < M && gk + 3 < FIN) ? x[(size_t)gr * FIN + gk + 3] : 0.f;
            }
        }
    };
    auto issueB = [&](int kt, int buf) {
        #pragma unroll
        for (int i = 0; i < 2; ++i) {
            const unsigned short* gp = W1s + ((size_t)kt * 1024 + (size_t)(i * 512 + t)) * 8;
            unsigned short* lp = &Bs[buf][(i * 512 + wave * 64) * 8];
            __builtin_amdgcn_global_load_lds(
                (const __attribute__((address_space(1))) unsigned int*)gp,
                (__attribute__((address_space(3))) unsigned int*)lp, 16, 0, 0);
        }
    };
    auto writeA = [&](int buf) {
        #pragma unroll
        for (int i = 0; i < 4; ++i) {
            int quad = i * 512 + t;
            int row = quad >> 4, kq = quad & 15;
            __hip_bfloat162 lo2 = __float22bfloat162_rn(make_float2(areg[i].x, areg[i].y));
            __hip_bfloat162 hi2 = __float22bfloat162_rn(make_float2(areg[i].z, areg[i].w));
            unsigned int ulo, uhi;
            __builtin_memcpy(&ulo, &lo2, 4);
            __builtin_memcpy(&uhi, &hi2, 4);
            unsigned long long pk = ((unsigned long long)uhi << 32) | (unsigned long long)ulo;
            int us = row * 64 + ((kq * 4) ^ ((row & 7) << 3));
            *(unsigned long long*)(&As[buf][us]) = pk;
        }
    };
    auto compute = [&](int abuf, int bbuf) {
        short8_t af[2][2], bfr[2][4];
        #pragma unroll
        for (int ks = 0; ks < 2; ++ks) {
            int g = ks * 4 + u;
            #pragma unroll
            for (int mi = 0; mi < 2; ++mi) {
                int row = wm * 32 + mi * 16 + r;
                int us = row * 64 + ((g * 8) ^ ((row & 7) << 3));
                af[ks][mi] = *(const short8_t*)(&As[abuf][us]);
            }
            #pragma unroll
            for (int ni = 0; ni < 4; ++ni) {
                int c = wn * 64 + ni * 16 + r;
                bfr[ks][ni] = *(const short8_t*)(&Bs[bbuf][g * 1024 + c * 8]);
            }
        }
        #pragma unroll
        for (int ks = 0; ks < 2; ++ks)
            #pragma unroll
            for (int mi = 0; mi < 2; ++mi)
                #pragma unroll
                for (int ni = 0; ni < 4; ++ni)
                    acc[mi][ni] = __builtin_amdgcn_mfma_f32_16x16x32_bf16(af[ks][mi], bfr[ks][ni], acc[mi][ni], 0, 0, 0);
    };

    // prologue: tile 0 staged, tile 1 in flight
    issueA(0); issueB(0, 0);
    writeA(0);
    issueA(1); issueB(1, 1);
    asm volatile("s_waitcnt vmcnt(6) lgkmcnt(0)" ::: "memory");
    __builtin_amdgcn_sched_barrier(0);
    __builtin_amdgcn_s_barrier();
    __builtin_amdgcn_sched_barrier(0);

    for (int kt = 0; kt < KT1 - 2; ++kt) {
        compute(kt & 1, kt % 3);
        writeA((kt + 1) & 1);
        issueA(kt + 2);
        issueB(kt + 2, (kt + 2) % 3);
        asm volatile("s_waitcnt vmcnt(6) lgkmcnt(0)" ::: "memory");
        __builtin_amdgcn_sched_barrier(0);
        __builtin_amdgcn_s_barrier();
        __builtin_amdgcn_sched_barrier(0);
    }
    {
        const int kt = KT1 - 2;
        compute(kt & 1, kt % 3);
        writeA((kt + 1) & 1);
        __syncthreads();
    }
    compute((KT1 - 1) & 1, (KT1 - 1) % 3);

    // epilogue: C layout col=lane&15, row=(lane>>4)*4+reg; pre-scale by dinv[row]
    #pragma unroll
    for (int mi = 0; mi < 2; ++mi) {
        #pragma unroll
        for (int reg = 0; reg < 4; ++reg) {
            int grow = rowBase + wm * 32 + mi * 16 + u * 4 + reg;
            if (grow < M) {
                float dv = dinv[grow];
                #pragma unroll
                for (int ni = 0; ni < 4; ++ni) {
                    int gcol = wn * 64 + ni * 16 + r;
                    h[(size_t)grow * HID + gcol] = f2bf(dv * acc[mi][ni][reg]);
                }
            }
        }
    }
}

// ---------------- Aggregation 1 + bias + relu + @W2 fused ----------------
__global__ __launch_bounds__(256) void agg1(const unsigned short* __restrict__ h,
                                            const int* __restrict__ ptr,
                                            const int* __restrict__ deg,
                                            const int* __restrict__ csr,
                                            const float* __restrict__ dinv,
                                            const float* __restrict__ b1,
                                            const float* __restrict__ W2,
                                            float* __restrict__ h2s, int n) {
    __shared__ float W2s[HID * NCLS];
    for (int i = threadIdx.x; i < HID * NCLS; i += 256) W2s[i] = W2[i];
    __syncthreads();
    int wave = threadIdx.x >> 6, lane = threadIdx.x & 63;
    int v = blockIdx.x * 4 + wave;
    if (v >= n) return;
    const int fr = lane & 15, g = lane >> 4;
    int p0 = ptr[v];
    int total = deg[v];                 // in-edges + self (all in csr)
    float acc[8] = {};
    #pragma unroll 8
    for (int j = g; j < total; j += 4) {
        int s = csr[p0 + j];
        uint4 q = *(const uint4*)(h + (size_t)s * HID + fr * 8);
        unsigned int w[4] = {q.x, q.y, q.z, q.w};
        #pragma unroll
        for (int p = 0; p < 4; ++p) {
            acc[p * 2 + 0] += bf2f((unsigned short)(w[p] & 0xffffu));
            acc[p * 2 + 1] += bf2f((unsigned short)(w[p] >> 16));
        }
    }
    #pragma unroll
    for (int e = 0; e < 8; ++e) {
        acc[e] += __shfl_xor(acc[e], 16, 64);
        acc[e] += __shfl_xor(acc[e], 32, 64);
    }
    float dv = dinv[v];
    float p[NCLS];
    #pragma unroll
    for (int c = 0; c < NCLS; ++c) p[c] = 0.f;
    #pragma unroll
    for (int e = 0; e < 8; ++e) {
        int f = fr * 8 + e;
        float val = fmaxf(dv * acc[e] + b1[f], 0.f);
        #pragma unroll
        for (int c = 0; c < NCLS; ++c) p[c] += val * W2s[f * NCLS + c];
    }
    #pragma unroll
    for (int off = 8; off >= 1; off >>= 1)
        #pragma unroll
        for (int c = 0; c < NCLS; ++c)
            p[c] += __shfl_xor(p[c], off, 64);
    if (lane == 0) {
        #pragma unroll
        for (int c = 0; c < NCLS; ++c) h2s[(size_t)v * 8 + c] = dv * p[c];  // pre-scaled
        h2s[(size_t)v * 8 + 7] = 0.f;
    }
}

// ---------------- Aggregation 2 + bias ----------------
__global__ __launch_bounds__(256) void agg2(const float* __restrict__ h2s,
                                            const int* __restrict__ ptr,
                                            const int* __restrict__ deg,
                                            const int* __restrict__ csr,
                                            const float* __restrict__ dinv,
                                            const float* __restrict__ b2,
                                            float* __restrict__ out, int n) {
    int wave = threadIdx.x >> 6, lane = threadIdx.x & 63;
    int half = lane >> 5;
    int c = lane & 7, g = (lane >> 3) & 3;
    int v = blockIdx.x * 8 + wave * 2 + half;
    if (v >= n) return;
    int p0 = ptr[v], total = deg[v];
    float acc = 0.f;
    #pragma unroll 8
    for (int j = g; j < total; j += 4) {
        int s = csr[p0 + j];
        acc += h2s[(size_t)s * 8 + c];
    }
    acc += __shfl_xor(acc, 8, 64);
    acc += __shfl_xor(acc, 16, 64);
    if (g == 0 && c < NCLS) out[(size_t)v * NCLS + c] = dinv[v] * acc + b2[c];
}

extern "C" void kernel_launch(void* const* d_in, const int* in_sizes, int n_in,
                              void* d_out, int out_size, void* d_ws, size_t ws_size,
                              hipStream_t stream) {
    const float* x  = (const float*)d_in[0];
    const int*   ei = (const int*)d_in[1];    // int64 in reference but JAX x64-off => int32
    const float* W1 = (const float*)d_in[2];
    const float* b1 = (const float*)d_in[3];
    const float* W2 = (const float*)d_in[4];
    const float* b2 = (const float*)d_in[5];
    float* out = (float*)d_out;

    const int N = NNODES;
    const int E = in_sizes[1] / 2;
    const int* src = ei;
    const int* dst = ei + E;
    const int NB = (N + 255) / 256;           // scan blocks (196 <= 256)

    char* ws = (char*)d_ws;
    size_t off = 0;
    auto alloc = [&](size_t bytes) {
        void* p = ws + off;
        off += (bytes + 255) & ~(size_t)255;
        return p;
    };
    int*   deg    = (int*)alloc((size_t)N * 4);
    float* dinv   = (float*)alloc((size_t)N * 4);
    int*   ptr    = (int*)alloc((size_t)N * 4);
    int*   cursor = (int*)alloc((size_t)N * 4);
    int*   blksum = (int*)alloc((size_t)NB * 4);
    int*   csr    = (int*)alloc((size_t)(E + N) * 4);
    unsigned short* W1s = (unsigned short*)alloc((size_t)KT1 * 1024 * 8 * 2);
    unsigned short* h   = (unsigned short*)alloc((size_t)N * HID * 2);
    float* h2s    = (float*)alloc((size_t)N * 8 * 4);

    init_deg<<<NB, 256, 0, stream>>>(deg, N);
    count_deg4<<<(E / 4 + 255) / 256, 256, 0, stream>>>(dst, E, deg);
    scan_part<<<NB, 256, 0, stream>>>(deg, blksum, N);
    scan_block<<<1, 256, 0, stream>>>(blksum, NB);
    scan_apply<<<NB, 256, 0, stream>>>(deg, blksum, ptr, cursor, dinv, csr, N);
    fill_csr4<<<(E / 4 + 255) / 256, 256, 0, stream>>>(src, dst, E, cursor, csr);
    prep_w1<<<(KT1 * 1024 + 255) / 256, 256, 0, stream>>>(W1, W1s);
    gemm1<<<(N + BM - 1) / BM, 512, 0, stream>>>(x, W1s, dinv, h, N);
    agg1<<<(N + 3) / 4, 256, 0, stream>>>(h, ptr, deg, csr, dinv, b1, W2, h2s, N);
    agg2<<<(N + 7) / 8, 256, 0, stream>>>(h2s, ptr, deg, csr, dinv, b2, out, N);
}